// Round 7
// baseline (1933.484 us; speedup 1.0000x reference)
//
#include <hip/hip_runtime.h>

#define T 3
#define E 500000
#define F 128
#define H 64
#define B 1024

#define BLK_E 64
#define LR 17   // red row stride (odd -> conflict-free)

// ---- helpers ----------------------------------------------------------

__device__ __forceinline__ float tanh_fast(float x) {
  // tanh(x) = 1 - 2/(exp(2x)+1); robust at +-inf
  float e = __expf(2.0f * x);
  return 1.0f - 2.0f / (e + 1.0f);
}

// xs layout: [f][64] stride 64, element (f,e) stored at column
// (( (e>>2) ^ (f&15) )<<2) | (e&3).  -> b128 reads conflict-free & aligned.
__device__ __forceinline__ int swz(int f, int e) {
  return ((((e >> 2) ^ (f & 15)) << 2) | (e & 3));
}

// ---- kernel 0: zero accumulators + counters ---------------------------

__global__ void k_init(float* __restrict__ acc, float* __restrict__ ssum,
                       unsigned* __restrict__ cnt) {
  int idx = blockIdx.x * blockDim.x + threadIdx.x;
  if (idx < T * B * F) acc[idx] = 0.0f;
  if (idx < T * B) {
    ssum[idx] = 0.0f;
    cnt[idx] = 0u;
  }
}

// ---- kernel 1: histogram of edges per (t, graph) ----------------------

__global__ __launch_bounds__(256) void k_hist(
    const int* __restrict__ batch, unsigned* __restrict__ cnt) {
  int t = blockIdx.y;
  int e = blockIdx.x * 256 + threadIdx.x;
  if (e >= E) return;
  atomicAdd(&cnt[t * B + batch[(size_t)t * E + e]], 1u);
}

// ---- kernel 2: prefix sums --------------------------------------------

__global__ void k_scan(const unsigned* __restrict__ cnt,
                       unsigned* __restrict__ cursor) {
  __shared__ unsigned s[B];
  int tid = threadIdx.x;
  for (int t = 0; t < T; ++t) {
    unsigned v = cnt[t * B + tid];
    s[tid] = v;
    __syncthreads();
    for (int d = 1; d < B; d <<= 1) {
      unsigned x = (tid >= d) ? s[tid - d] : 0u;
      __syncthreads();
      s[tid] += x;
      __syncthreads();
    }
    cursor[t * B + tid] = s[tid] - v;  // exclusive scan
    __syncthreads();
  }
}

// ---- kernel 3: counting-sort scatter of edge ids ----------------------

__global__ __launch_bounds__(256) void k_scatter(
    const int* __restrict__ batch, unsigned* __restrict__ cursor,
    unsigned* __restrict__ eid) {
  int t = blockIdx.y;
  int e = blockIdx.x * 256 + threadIdx.x;
  if (e >= E) return;
  int b = batch[(size_t)t * E + e];
  unsigned pos = atomicAdd(&cursor[t * B + b], 1u);
  eid[(size_t)t * E + pos] = e;
}

// ---- kernel 4: fused score + exp + segment-aggregated scatter ---------
// Edges arrive sorted by graph. One pass over ea:
//   out_acc[b][f] += sum_{edges of b} exp(score) * ea[f]
// Segment aggregation in registers -> one atomic per (segment, f) instead
// of per (edge, f): write traffic 768MB -> ~25MB. No max-subtraction:
// |score| <= ||W2||_1 ~ 6, exp() cannot overflow.

__global__ __launch_bounds__(256, 4) void k_fused(
    const float* __restrict__ ea, const int* __restrict__ batch,
    const unsigned* __restrict__ eid,
    const float* __restrict__ W1, const float* __restrict__ b1,
    const float* __restrict__ W2, const float* __restrict__ b2,
    float* __restrict__ acc, float* __restrict__ ssum) {
  __shared__ __align__(16) float xs[F * 64];  // 32 KB swizzled [f][e]
  __shared__ float red[BLK_E * LR];           // 4.4 KB
  __shared__ float exl[BLK_E];
  __shared__ int bbl[BLK_E];
  __shared__ int eidl[BLK_E];

  int t = blockIdx.y;
  int tid = threadIdx.x;
  int e0 = blockIdx.x * BLK_E;

  // load this block's sorted edge ids + their graphs (batch is L2-hot)
  if (tid < BLK_E) {
    int p = e0 + tid;
    int pc = p < E ? p : E - 1;  // clamp tail; predicated out later
    int id = (int)eid[(size_t)t * E + pc];
    eidl[tid] = id;
    bbl[tid] = batch[(size_t)t * E + id];
  }
  __syncthreads();

  // stage gathered rows transposed+swizzled; 512B-contiguous global reads
  const float* eag = ea + (size_t)t * E * (size_t)F;
#pragma unroll
  for (int k = 0; k < (BLK_E * F) / 256; ++k) {
    int idx = tid + k * 256;
    int r = idx >> 7;  // edge slot
    int f = idx & 127;
    xs[f * 64 + swz(f, r)] = eag[(size_t)eidl[r] * F + f];
  }
  __syncthreads();

  // register-tiled GEMM: 4 edges (te) x 4 hidden (tj) per thread
  int te = tid & 15;   // edge group: e = 4*te .. 4*te+3
  int tj = tid >> 4;   // j group:   j = 4*tj .. 4*tj+3

  float acc4[4][4];
#pragma unroll
  for (int i = 0; i < 4; ++i)
#pragma unroll
    for (int j = 0; j < 4; ++j) acc4[i][j] = 0.0f;

  const float4* wq = (const float4*)(W1 + (size_t)t * F * H);  // [f][16]
#pragma unroll 4
  for (int f = 0; f < F; ++f) {
    float4 xv = *(const float4*)&xs[f * 64 + ((te ^ (f & 15)) << 2)];
    float4 w = wq[f * 16 + tj];        // global, L1/L2-hot
    acc4[0][0] = fmaf(xv.x, w.x, acc4[0][0]);
    acc4[0][1] = fmaf(xv.x, w.y, acc4[0][1]);
    acc4[0][2] = fmaf(xv.x, w.z, acc4[0][2]);
    acc4[0][3] = fmaf(xv.x, w.w, acc4[0][3]);
    acc4[1][0] = fmaf(xv.y, w.x, acc4[1][0]);
    acc4[1][1] = fmaf(xv.y, w.y, acc4[1][1]);
    acc4[1][2] = fmaf(xv.y, w.z, acc4[1][2]);
    acc4[1][3] = fmaf(xv.y, w.w, acc4[1][3]);
    acc4[2][0] = fmaf(xv.z, w.x, acc4[2][0]);
    acc4[2][1] = fmaf(xv.z, w.y, acc4[2][1]);
    acc4[2][2] = fmaf(xv.z, w.z, acc4[2][2]);
    acc4[2][3] = fmaf(xv.z, w.w, acc4[2][3]);
    acc4[3][0] = fmaf(xv.w, w.x, acc4[3][0]);
    acc4[3][1] = fmaf(xv.w, w.y, acc4[3][1]);
    acc4[3][2] = fmaf(xv.w, w.z, acc4[3][2]);
    acc4[3][3] = fmaf(xv.w, w.w, acc4[3][3]);
  }

  // tanh + W2 slice -> per-edge partials (red stride 17: conflict-free)
  float b10 = b1[t * H + 4 * tj + 0], b11 = b1[t * H + 4 * tj + 1];
  float b12 = b1[t * H + 4 * tj + 2], b13 = b1[t * H + 4 * tj + 3];
  float w20 = W2[t * H + 4 * tj + 0], w21 = W2[t * H + 4 * tj + 1];
  float w22 = W2[t * H + 4 * tj + 2], w23 = W2[t * H + 4 * tj + 3];

#pragma unroll
  for (int i = 0; i < 4; ++i) {
    float s = tanh_fast(acc4[i][0] + b10) * w20;
    s = fmaf(tanh_fast(acc4[i][1] + b11), w21, s);
    s = fmaf(tanh_fast(acc4[i][2] + b12), w22, s);
    s = fmaf(tanh_fast(acc4[i][3] + b13), w23, s);
    red[(4 * te + i) * LR + tj] = s;
  }
  __syncthreads();

  if (tid < BLK_E) {
    float sc = b2[t];
#pragma unroll
    for (int k = 0; k < 16; ++k) sc += red[tid * LR + k];
    float ex = __expf(sc);
    exl[tid] = ex;
    if (e0 + tid < E) atomicAdd(&ssum[t * B + bbl[tid]], ex);
  }
  __syncthreads();

  // segment-aggregated scatter: wave wv owns 16 sorted edges; lane l owns
  // f=l and f=l+64. Accumulate in registers while graph unchanged; flush
  // one atomic pair per segment boundary.
  int wv = tid >> 6;
  int l = tid & 63;
  float* acct = acc + (size_t)t * B * F;
  float a0 = 0.0f, a1 = 0.0f;
  int prev = -1;
  for (int i = 0; i < 16; ++i) {
    int eloc = wv * 16 + i;
    if (e0 + eloc >= E) break;        // uniform (tail block only)
    int b = bbl[eloc];                // wave-uniform broadcast
    if (b != prev) {
      if (prev >= 0) {
        atomicAdd(acct + (size_t)prev * F + l, a0);
        atomicAdd(acct + (size_t)prev * F + l + 64, a1);
      }
      prev = b;
      a0 = 0.0f;
      a1 = 0.0f;
    }
    float exv = exl[eloc];
    a0 = fmaf(xs[l * 64 + swz(l, eloc)], exv, a0);
    a1 = fmaf(xs[(l + 64) * 64 + swz(l + 64, eloc)], exv, a1);
  }
  if (prev >= 0) {
    atomicAdd(acct + (size_t)prev * F + l, a0);
    atomicAdd(acct + (size_t)prev * F + l + 64, a1);
  }
}

// ---- kernel 5: normalize + mean over types ----------------------------

__global__ __launch_bounds__(256) void k_final(
    const float* __restrict__ acc, const float* __restrict__ ssum,
    float* __restrict__ out) {
  int idx = blockIdx.x * 256 + threadIdx.x;  // b*F + f
  if (idx >= B * F) return;
  int b = idx >> 7;
  float s = 0.0f;
#pragma unroll
  for (int t = 0; t < T; ++t)
    s += acc[(size_t)t * B * F + idx] / ssum[t * B + b];
  out[idx] = s * (1.0f / 3.0f);
}

// ---- launch ------------------------------------------------------------

extern "C" void kernel_launch(void* const* d_in, const int* in_sizes, int n_in,
                              void* d_out, int out_size, void* d_ws, size_t ws_size,
                              hipStream_t stream) {
  const float* ea    = (const float*)d_in[0];
  const int*   batch = (const int*)d_in[1];
  const float* W1    = (const float*)d_in[2];
  const float* b1    = (const float*)d_in[3];
  const float* W2    = (const float*)d_in[4];
  const float* b2    = (const float*)d_in[5];
  float* out = (float*)d_out;

  // workspace: acc 1.5MB + ssum/cnt/cursor 36KB + eid 6MB  (~7.6 MB)
  float*    acc    = (float*)d_ws;                     // T*B*F f32
  float*    ssum   = acc + (size_t)T * B * F;          // T*B f32
  unsigned* cnt    = (unsigned*)(ssum + T * B);        // T*B u32
  unsigned* cursor = cnt + T * B;                      // T*B u32
  unsigned* eid    = cursor + T * B;                   // T*E u32

  k_init<<<(T * B * F + 255) / 256, 256, 0, stream>>>(acc, ssum, cnt);

  dim3 ge((E + 255) / 256, T);
  k_hist<<<ge, 256, 0, stream>>>(batch, cnt);
  k_scan<<<1, B, 0, stream>>>(cnt, cursor);
  k_scatter<<<ge, 256, 0, stream>>>(batch, cursor, eid);

  dim3 gs((E + BLK_E - 1) / BLK_E, T);
  k_fused<<<gs, 256, 0, stream>>>(ea, batch, eid, W1, b1, W2, b2, acc, ssum);

  k_final<<<(B * F + 255) / 256, 256, 0, stream>>>(acc, ssum, out);
}

// Round 8
// 1776.103 us; speedup vs baseline: 1.0886x; 1.0886x over previous
//
#include <hip/hip_runtime.h>

#define T 3
#define E 500000
#define F 128
#define H 64
#define B 1024

#define BLK_E 64
#define LE 65   // xs row stride (odd -> <=2-way read banks)
#define LR 17   // red row stride

#define EMASK 0x7FFFF  // e < 2^19; graph packed in bits 19..28

// ---- helpers ----------------------------------------------------------

__device__ __forceinline__ float tanh_fast(float x) {
  // tanh(x) = 1 - 2/(exp(2x)+1); robust at +-inf
  float e = __expf(2.0f * x);
  return 1.0f - 2.0f / (e + 1.0f);
}

// ---- kernel 0: zero accumulators + counters ---------------------------

__global__ void k_init(float* __restrict__ acc, float* __restrict__ ssum,
                       unsigned* __restrict__ cnt) {
  int idx = blockIdx.x * blockDim.x + threadIdx.x;
  if (idx < T * B * F) acc[idx] = 0.0f;
  if (idx < T * B) {
    ssum[idx] = 0.0f;
    cnt[idx] = 0u;
  }
}

// ---- kernel 1: histogram of edges per (t, graph) ----------------------

__global__ __launch_bounds__(256) void k_hist(
    const int* __restrict__ batch, unsigned* __restrict__ cnt) {
  int t = blockIdx.y;
  int e = blockIdx.x * 256 + threadIdx.x;
  if (e >= E) return;
  atomicAdd(&cnt[t * B + batch[(size_t)t * E + e]], 1u);
}

// ---- kernel 2: prefix sums --------------------------------------------

__global__ void k_scan(const unsigned* __restrict__ cnt,
                       unsigned* __restrict__ cursor) {
  __shared__ unsigned s[B];
  int tid = threadIdx.x;
  for (int t = 0; t < T; ++t) {
    unsigned v = cnt[t * B + tid];
    s[tid] = v;
    __syncthreads();
    for (int d = 1; d < B; d <<= 1) {
      unsigned x = (tid >= d) ? s[tid - d] : 0u;
      __syncthreads();
      s[tid] += x;
      __syncthreads();
    }
    cursor[t * B + tid] = s[tid] - v;  // exclusive scan
    __syncthreads();
  }
}

// ---- kernel 3: counting-sort scatter; pack (graph<<19)|edge -----------

__global__ __launch_bounds__(256) void k_scatter(
    const int* __restrict__ batch, unsigned* __restrict__ cursor,
    unsigned* __restrict__ eid) {
  int t = blockIdx.y;
  int e = blockIdx.x * 256 + threadIdx.x;
  if (e >= E) return;
  int b = batch[(size_t)t * E + e];
  unsigned pos = atomicAdd(&cursor[t * B + b], 1u);
  eid[(size_t)t * E + pos] = (unsigned)e | ((unsigned)b << 19);
}

// ---- kernel 4: fused score + exp + segment-aggregated scatter ---------
// Edges arrive sorted by graph; out_acc[b][f] += sum ex*ea[f], one atomic
// per (segment,f). Gather is REGISTER-staged (k_pool pattern): 8 independent
// global_load_dwordx4 per thread in flight, then transpose to LDS.
// No max-subtraction: |score| <= ||W2||_1 ~ 6, exp() cannot overflow.

__global__ __launch_bounds__(256, 4) void k_fused(
    const float* __restrict__ ea, const unsigned* __restrict__ eid,
    const float* __restrict__ W1, const float* __restrict__ b1,
    const float* __restrict__ W2, const float* __restrict__ b2,
    float* __restrict__ acc, float* __restrict__ ssum) {
  __shared__ float xs[F * LE];       // 33.3 KB  [f][e] pad-65
  __shared__ float red[BLK_E * LR];  // 4.4 KB
  __shared__ float exl[BLK_E];
  __shared__ int bbl[BLK_E];
  __shared__ int eidl[BLK_E];

  int t = blockIdx.y;
  int tid = threadIdx.x;
  int e0 = blockIdx.x * BLK_E;

  if (tid < BLK_E) {
    int p = e0 + tid;
    int pc = p < E ? p : E - 1;  // clamp tail; predicated out later
    unsigned pk = eid[(size_t)t * E + pc];
    eidl[tid] = (int)(pk & EMASK);
    bbl[tid] = (int)(pk >> 19);
  }
  __syncthreads();

  // ---- register-staged gather: tile = 64 rows x 32 float4 ----
  const float* eag = ea + (size_t)t * E * (size_t)F;
  int c = tid & 31;            // float4 column
  int r0 = tid >> 5;           // base row (0..7)
  float4 v[8];
  int rows[8];
#pragma unroll
  for (int k = 0; k < 8; ++k) rows[k] = r0 + k * 8;
  int ids[8];
#pragma unroll
  for (int k = 0; k < 8; ++k) ids[k] = eidl[rows[k]];  // 8 indep ds_reads
#pragma unroll
  for (int k = 0; k < 8; ++k)   // 8 indep dwordx4 loads in flight
    v[k] = *(const float4*)(eag + (size_t)ids[k] * F + c * 4);
#pragma unroll
  for (int k = 0; k < 8; ++k) { // transpose to LDS (4-way banks, cheap)
    xs[(4 * c + 0) * LE + rows[k]] = v[k].x;
    xs[(4 * c + 1) * LE + rows[k]] = v[k].y;
    xs[(4 * c + 2) * LE + rows[k]] = v[k].z;
    xs[(4 * c + 3) * LE + rows[k]] = v[k].w;
  }
  __syncthreads();

  // ---- register-tiled GEMM: 4 edges (te) x 4 hidden (tj) per thread ----
  int te = tid & 15;
  int tj = tid >> 4;

  float acc4[4][4];
#pragma unroll
  for (int i = 0; i < 4; ++i)
#pragma unroll
    for (int j = 0; j < 4; ++j) acc4[i][j] = 0.0f;

  const float4* wq = (const float4*)(W1 + (size_t)t * F * H);  // [f][16]
#pragma unroll 4
  for (int f = 0; f < F; ++f) {
    float x0 = xs[f * LE + 4 * te + 0];
    float x1 = xs[f * LE + 4 * te + 1];
    float x2 = xs[f * LE + 4 * te + 2];
    float x3 = xs[f * LE + 4 * te + 3];
    float4 w = wq[f * 16 + tj];        // global, L1-hot
    acc4[0][0] = fmaf(x0, w.x, acc4[0][0]);
    acc4[0][1] = fmaf(x0, w.y, acc4[0][1]);
    acc4[0][2] = fmaf(x0, w.z, acc4[0][2]);
    acc4[0][3] = fmaf(x0, w.w, acc4[0][3]);
    acc4[1][0] = fmaf(x1, w.x, acc4[1][0]);
    acc4[1][1] = fmaf(x1, w.y, acc4[1][1]);
    acc4[1][2] = fmaf(x1, w.z, acc4[1][2]);
    acc4[1][3] = fmaf(x1, w.w, acc4[1][3]);
    acc4[2][0] = fmaf(x2, w.x, acc4[2][0]);
    acc4[2][1] = fmaf(x2, w.y, acc4[2][1]);
    acc4[2][2] = fmaf(x2, w.z, acc4[2][2]);
    acc4[2][3] = fmaf(x2, w.w, acc4[2][3]);
    acc4[3][0] = fmaf(x3, w.x, acc4[3][0]);
    acc4[3][1] = fmaf(x3, w.y, acc4[3][1]);
    acc4[3][2] = fmaf(x3, w.z, acc4[3][2]);
    acc4[3][3] = fmaf(x3, w.w, acc4[3][3]);
  }

  // ---- tanh + W2 slice -> per-edge partials ----
  float b10 = b1[t * H + 4 * tj + 0], b11 = b1[t * H + 4 * tj + 1];
  float b12 = b1[t * H + 4 * tj + 2], b13 = b1[t * H + 4 * tj + 3];
  float w20 = W2[t * H + 4 * tj + 0], w21 = W2[t * H + 4 * tj + 1];
  float w22 = W2[t * H + 4 * tj + 2], w23 = W2[t * H + 4 * tj + 3];

#pragma unroll
  for (int i = 0; i < 4; ++i) {
    float s = tanh_fast(acc4[i][0] + b10) * w20;
    s = fmaf(tanh_fast(acc4[i][1] + b11), w21, s);
    s = fmaf(tanh_fast(acc4[i][2] + b12), w22, s);
    s = fmaf(tanh_fast(acc4[i][3] + b13), w23, s);
    red[(4 * te + i) * LR + tj] = s;
  }
  __syncthreads();

  if (tid < BLK_E) {
    float sc = b2[t];
#pragma unroll
    for (int k = 0; k < 16; ++k) sc += red[tid * LR + k];
    float ex = __expf(sc);
    exl[tid] = ex;
    if (e0 + tid < E) atomicAdd(&ssum[t * B + bbl[tid]], ex);
  }
  __syncthreads();

  // ---- segment-aggregated scatter: wave wv owns 16 sorted edges ----
  int wv = tid >> 6;
  int l = tid & 63;
  float* acct = acc + (size_t)t * B * F;
  float a0 = 0.0f, a1 = 0.0f;
  int prev = -1;
  for (int i = 0; i < 16; ++i) {
    int eloc = wv * 16 + i;
    if (e0 + eloc >= E) break;        // uniform (tail block only)
    int b = bbl[eloc];                // wave-uniform
    if (b != prev) {
      if (prev >= 0) {
        atomicAdd(acct + (size_t)prev * F + l, a0);
        atomicAdd(acct + (size_t)prev * F + l + 64, a1);
      }
      prev = b;
      a0 = 0.0f;
      a1 = 0.0f;
    }
    float exv = exl[eloc];
    a0 = fmaf(xs[l * LE + eloc], exv, a0);
    a1 = fmaf(xs[(l + 64) * LE + eloc], exv, a1);
  }
  if (prev >= 0) {
    atomicAdd(acct + (size_t)prev * F + l, a0);
    atomicAdd(acct + (size_t)prev * F + l + 64, a1);
  }
}

// ---- kernel 5: normalize + mean over types ----------------------------

__global__ __launch_bounds__(256) void k_final(
    const float* __restrict__ acc, const float* __restrict__ ssum,
    float* __restrict__ out) {
  int idx = blockIdx.x * 256 + threadIdx.x;  // b*F + f
  if (idx >= B * F) return;
  int b = idx >> 7;
  float s = 0.0f;
#pragma unroll
  for (int t = 0; t < T; ++t)
    s += acc[(size_t)t * B * F + idx] / ssum[t * B + b];
  out[idx] = s * (1.0f / 3.0f);
}

// ---- launch ------------------------------------------------------------

extern "C" void kernel_launch(void* const* d_in, const int* in_sizes, int n_in,
                              void* d_out, int out_size, void* d_ws, size_t ws_size,
                              hipStream_t stream) {
  const float* ea    = (const float*)d_in[0];
  const int*   batch = (const int*)d_in[1];
  const float* W1    = (const float*)d_in[2];
  const float* b1    = (const float*)d_in[3];
  const float* W2    = (const float*)d_in[4];
  const float* b2    = (const float*)d_in[5];
  float* out = (float*)d_out;

  // workspace: acc 1.5MB + ssum/cnt/cursor 36KB + eid 6MB  (~7.6 MB)
  float*    acc    = (float*)d_ws;                     // T*B*F f32
  float*    ssum   = acc + (size_t)T * B * F;          // T*B f32
  unsigned* cnt    = (unsigned*)(ssum + T * B);        // T*B u32
  unsigned* cursor = cnt + T * B;                      // T*B u32
  unsigned* eid    = cursor + T * B;                   // T*E u32

  k_init<<<(T * B * F + 255) / 256, 256, 0, stream>>>(acc, ssum, cnt);

  dim3 ge((E + 255) / 256, T);
  k_hist<<<ge, 256, 0, stream>>>(batch, cnt);
  k_scan<<<1, B, 0, stream>>>(cnt, cursor);
  k_scatter<<<ge, 256, 0, stream>>>(batch, cursor, eid);

  dim3 gs((E + BLK_E - 1) / BLK_E, T);
  k_fused<<<gs, 256, 0, stream>>>(ea, eid, W1, b1, W2, b2, acc, ssum);

  k_final<<<(B * F + 255) / 256, 256, 0, stream>>>(acc, ssum, out);
}